// Round 1
// baseline (2788.749 us; speedup 1.0000x reference)
//
#include <hip/hip_runtime.h>
#include <hip/hip_bf16.h>

#define N_USERS 100000
#define N_ITEMS 50000
#define NNZ_EDGES 1600000
#define DIM 64

// ---------------------------------------------------------------------------
// Dense GEMM: Y[nrows,64] = X[nrows,64] @ W[64,64]
// Block = 256 threads = 4 rows x 64 cols. W staged in LDS (16 KB), 4 X-rows
// staged in LDS (1 KB). sW[k][c] access: 64 consecutive c per wave -> 2
// lanes/bank (free). sX[r][k] is a broadcast.
// ---------------------------------------------------------------------------
__global__ __launch_bounds__(256) void gemm64_kernel(
    const float* __restrict__ X, const float* __restrict__ W,
    float* __restrict__ Y, int nrows) {
  __shared__ float sW[64][64];
  __shared__ float sX[4][64];
  const int tid = threadIdx.x;

  // Load W (4096 floats) cooperatively, coalesced.
  #pragma unroll
  for (int i = 0; i < 16; ++i) {
    int idx = tid + i * 256;
    sW[idx >> 6][idx & 63] = W[idx];
  }

  const int r = tid >> 6;        // 0..3
  const int c = tid & 63;        // 0..63
  const int row = blockIdx.x * 4 + r;
  if (row < nrows) sX[r][c] = X[row * DIM + c];
  __syncthreads();

  if (row < nrows) {
    float acc = 0.f;
    #pragma unroll
    for (int k = 0; k < DIM; ++k) acc = fmaf(sX[r][k], sW[k][c], acc);
    Y[row * DIM + c] = acc;
  }
}

// ---------------------------------------------------------------------------
// Edge-parallel SpMM, both directions in one pass.
// 16 threads per edge; thread owns one float4 chunk of the 64-dim feature.
// Gathers are coalesced 256B per edge; scatters are f32 atomics (L2).
// ---------------------------------------------------------------------------
__global__ __launch_bounds__(256) void spmm_edges_kernel(
    const int* __restrict__ rows, const int* __restrict__ cols,
    const float* __restrict__ vals,
    const float* __restrict__ xw_user, const float* __restrict__ xw_item,
    float* __restrict__ out_user, float* __restrict__ out_item, int nnz) {
  const int t = blockIdx.x * 256 + threadIdx.x;
  const int e = t >> 4;
  if (e >= nnz) return;
  const int chunk = t & 15;

  const int r = rows[e];
  const int c = cols[e];
  const float v = vals[e];

  const float4 a = ((const float4*)(xw_item + (size_t)c * DIM))[chunk];
  const float4 b = ((const float4*)(xw_user + (size_t)r * DIM))[chunk];

  float* ou = out_user + (size_t)r * DIM + chunk * 4;
  float* oi = out_item + (size_t)c * DIM + chunk * 4;
  atomicAdd(ou + 0, v * a.x);
  atomicAdd(ou + 1, v * a.y);
  atomicAdd(ou + 2, v * a.z);
  atomicAdd(ou + 3, v * a.w);
  atomicAdd(oi + 0, v * b.x);
  atomicAdd(oi + 1, v * b.y);
  atomicAdd(oi + 2, v * b.z);
  atomicAdd(oi + 3, v * b.w);
}

// ---------------------------------------------------------------------------
// In-place ReLU over the accumulated output (float4, grid-stride).
// ---------------------------------------------------------------------------
__global__ __launch_bounds__(256) void relu_kernel(float* __restrict__ out, int n4) {
  float4* p = (float4*)out;
  for (int i = blockIdx.x * 256 + threadIdx.x; i < n4; i += gridDim.x * 256) {
    float4 v = p[i];
    v.x = fmaxf(v.x, 0.f);
    v.y = fmaxf(v.y, 0.f);
    v.z = fmaxf(v.z, 0.f);
    v.w = fmaxf(v.w, 0.f);
    p[i] = v;
  }
}

extern "C" void kernel_launch(void* const* d_in, const int* in_sizes, int n_in,
                              void* d_out, int out_size, void* d_ws, size_t ws_size,
                              hipStream_t stream) {
  const float* user_x      = (const float*)d_in[0];   // [100000,64]
  const float* item_x      = (const float*)d_in[1];   // [50000,64]
  const float* user_weight = (const float*)d_in[2];   // [64,64]
  const float* item_weight = (const float*)d_in[3];   // [64,64]
  const int*   ui_rows     = (const int*)d_in[4];     // [NNZ]
  const int*   ui_cols     = (const int*)d_in[5];     // [NNZ]
  const float* ui_vals     = (const float*)d_in[6];   // [NNZ]

  float* out_user = (float*)d_out;                       // [100000,64]
  float* out_item = (float*)d_out + (size_t)N_USERS * DIM; // [50000,64]

  float* xw_user = (float*)d_ws;                          // 25.6 MB
  float* xw_item = (float*)d_ws + (size_t)N_USERS * DIM;  // +12.8 MB

  // Zero the output accumulators (harness poisons d_out with 0xAA).
  hipMemsetAsync(d_out, 0, (size_t)out_size * sizeof(float), stream);

  // Dense projections into workspace.
  gemm64_kernel<<<(N_USERS + 3) / 4, 256, 0, stream>>>(user_x, user_weight, xw_user, N_USERS);
  gemm64_kernel<<<(N_ITEMS + 3) / 4, 256, 0, stream>>>(item_x, item_weight, xw_item, N_ITEMS);

  // Scatter both SpMM directions.
  const int nthreads = NNZ_EDGES * 16;
  spmm_edges_kernel<<<(nthreads + 255) / 256, 256, 0, stream>>>(
      ui_rows, ui_cols, ui_vals, xw_user, xw_item, out_user, out_item, NNZ_EDGES);

  // ReLU epilogue.
  const int n4 = out_size / 4;
  relu_kernel<<<2048, 256, 0, stream>>>((float*)d_out, n4);
}

// Round 2
// 756.929 us; speedup vs baseline: 3.6843x; 3.6843x over previous
//
#include <hip/hip_runtime.h>
#include <hip/hip_bf16.h>

#define N_USERS 100000
#define N_ITEMS 50000
#define NNZ_EDGES 1600000
#define DIM 64

// ---------------------------------------------------------------------------
// Dense GEMM: Y[nrows,64] = X[nrows,64] @ W[64,64]
// Block = 256 threads = 4 rows x 64 cols. W staged in LDS.
// ---------------------------------------------------------------------------
__global__ __launch_bounds__(256) void gemm64_kernel(
    const float* __restrict__ X, const float* __restrict__ W,
    float* __restrict__ Y, int nrows) {
  __shared__ float sW[64][64];
  __shared__ float sX[4][64];
  const int tid = threadIdx.x;

  #pragma unroll
  for (int i = 0; i < 16; ++i) {
    int idx = tid + i * 256;
    sW[idx >> 6][idx & 63] = W[idx];
  }

  const int r = tid >> 6;
  const int c = tid & 63;
  const int row = blockIdx.x * 4 + r;
  if (row < nrows) sX[r][c] = X[row * DIM + c];
  __syncthreads();

  if (row < nrows) {
    float acc = 0.f;
    #pragma unroll
    for (int k = 0; k < DIM; ++k) acc = fmaf(sX[r][k], sW[k][c], acc);
    Y[row * DIM + c] = acc;
  }
}

// ---------------------------------------------------------------------------
// Histogram: count edges per user-row and per item-col (int atomics).
// Counts accumulate into the "cursor" arrays (zeroed by memsetAsync before).
// ---------------------------------------------------------------------------
__global__ __launch_bounds__(256) void hist_kernel(
    const int* __restrict__ rows, const int* __restrict__ cols,
    int* __restrict__ ucnt, int* __restrict__ icnt, int nnz) {
  int i = blockIdx.x * 256 + threadIdx.x;
  if (i < nnz) {
    atomicAdd(&ucnt[rows[i]], 1);
    atomicAdd(&icnt[cols[i]], 1);
  }
}

// ---------------------------------------------------------------------------
// Exclusive scan of the two count arrays. Block 0 -> user (n=100000),
// block 1 -> item (n=50000). 1024 threads; wave-shuffle scan + LDS combine
// (2 barriers per 1024-chunk). Writes exclusive offsets to off[] AND back
// into cnt[] (which becomes the scatter cursor). off[n] = total at the end.
// ---------------------------------------------------------------------------
__global__ __launch_bounds__(1024) void scan_kernel(
    int* __restrict__ user_cnt, int* __restrict__ user_off,
    int* __restrict__ item_cnt, int* __restrict__ item_off) {
  __shared__ int s_w[16];
  int* cnt; int* off; int n;
  if (blockIdx.x == 0) { cnt = user_cnt; off = user_off; n = N_USERS; }
  else                 { cnt = item_cnt; off = item_off; n = N_ITEMS; }

  const int tid = threadIdx.x;
  const int lane = tid & 63;
  const int wid = tid >> 6;

  int running = 0;
  for (int base = 0; base < n; base += 1024) {
    const int i = base + tid;
    const int x = (i < n) ? cnt[i] : 0;

    // inclusive scan within the wave (64 lanes)
    int incl = x;
    #pragma unroll
    for (int d = 1; d < 64; d <<= 1) {
      int t = __shfl_up(incl, d);
      if (lane >= d) incl += t;
    }
    if (lane == 63) s_w[wid] = incl;
    __syncthreads();

    // scan the 16 wave totals in wave 0
    if (wid == 0) {
      int y = (lane < 16) ? s_w[lane] : 0;
      #pragma unroll
      for (int d = 1; d < 16; d <<= 1) {
        int t = __shfl_up(y, d);
        if (lane >= d) y += t;
      }
      if (lane < 16) s_w[lane] = y;
    }
    __syncthreads();

    const int wave_base = (wid == 0) ? 0 : s_w[wid - 1];
    const int excl = running + wave_base + (incl - x);
    if (i < n) { off[i] = excl; cnt[i] = excl; }
    const int chunk_total = s_w[15];
    __syncthreads();  // protect s_w before next chunk overwrites it
    running += chunk_total;
  }
  if (tid == 0) off[n] = running;
}

// ---------------------------------------------------------------------------
// Scatter edges into destination-sorted arrays (counting-sort placement).
// edges_u sorted by user row, payload (item col, val);
// edges_i sorted by item col, payload (user row, val).
// ---------------------------------------------------------------------------
__global__ __launch_bounds__(256) void scatter_kernel(
    const int* __restrict__ rows, const int* __restrict__ cols,
    const float* __restrict__ vals,
    int* __restrict__ ucur, int* __restrict__ icur,
    int2* __restrict__ edges_u, int2* __restrict__ edges_i, int nnz) {
  int i = blockIdx.x * 256 + threadIdx.x;
  if (i >= nnz) return;
  const int r = rows[i];
  const int c = cols[i];
  const int v = __float_as_int(vals[i]);
  const int pu = atomicAdd(&ucur[r], 1);
  edges_u[pu] = make_int2(c, v);
  const int pi = atomicAdd(&icur[c], 1);
  edges_i[pi] = make_int2(r, v);
}

// ---------------------------------------------------------------------------
// Segmented SpMM (gather form), fused ReLU. One 64-lane wave per destination
// row; lane = feature. Edges batch-loaded 64 at a time (coalesced), then
// broadcast across the wave via __shfl. No float atomics; out written once.
// ---------------------------------------------------------------------------
__global__ __launch_bounds__(256) void spmm_csr_kernel(
    const int* __restrict__ off, const int2* __restrict__ edges,
    const float* __restrict__ xw, float* __restrict__ out, int ndst) {
  const int wid = threadIdx.x >> 6;
  const int lane = threadIdx.x & 63;
  const int d = blockIdx.x * 4 + wid;
  if (d >= ndst) return;

  const int beg = off[d];
  const int end = off[d + 1];
  float acc = 0.f;

  for (int k = beg; k < end; k += 64) {
    const int nb = min(64, end - k);
    int src_r = 0, val_r = 0;
    if (lane < nb) {
      const int2 e = edges[k + lane];
      src_r = e.x;
      val_r = e.y;
    }
    for (int j = 0; j < nb; ++j) {
      const int src = __shfl(src_r, j);
      const float v = __int_as_float(__shfl(val_r, j));
      acc = fmaf(v, xw[(size_t)src * DIM + lane], acc);
    }
  }
  out[(size_t)d * DIM + lane] = fmaxf(acc, 0.f);
}

extern "C" void kernel_launch(void* const* d_in, const int* in_sizes, int n_in,
                              void* d_out, int out_size, void* d_ws, size_t ws_size,
                              hipStream_t stream) {
  const float* user_x      = (const float*)d_in[0];
  const float* item_x      = (const float*)d_in[1];
  const float* user_weight = (const float*)d_in[2];
  const float* item_weight = (const float*)d_in[3];
  const int*   ui_rows     = (const int*)d_in[4];
  const int*   ui_cols     = (const int*)d_in[5];
  const float* ui_vals     = (const float*)d_in[6];

  float* out_user = (float*)d_out;
  float* out_item = (float*)d_out + (size_t)N_USERS * DIM;

  // ---- workspace layout (4-byte words) -----------------------------------
  float* xw_user  = (float*)d_ws;                       // 6,400,000 f32
  float* xw_item  = xw_user + (size_t)N_USERS * DIM;    // 3,200,000 f32
  int*   user_off = (int*)(xw_item + (size_t)N_ITEMS * DIM); // 100,002
  int*   item_off = user_off + (N_USERS + 2);           // 50,002
  int*   user_cur = item_off + (N_ITEMS + 2);           // 100,002
  int*   item_cur = user_cur + (N_USERS + 2);           // 50,002 (contig w/ user_cur)
  int2*  edges_u  = (int2*)(item_cur + (N_ITEMS + 2));  // 1.6M int2 (8B-aligned)
  int2*  edges_i  = edges_u + NNZ_EDGES;                // 1.6M int2
  // total ~65.2 MB

  // Dense projections (independent of the sort pipeline).
  gemm64_kernel<<<(N_USERS + 3) / 4, 256, 0, stream>>>(user_x, user_weight, xw_user, N_USERS);
  gemm64_kernel<<<(N_ITEMS + 3) / 4, 256, 0, stream>>>(item_x, item_weight, xw_item, N_ITEMS);

  // Counting sort: zero counts -> histogram -> scan -> scatter.
  hipMemsetAsync(user_cur, 0, ((N_USERS + 2) + (N_ITEMS + 2)) * sizeof(int), stream);
  hist_kernel<<<(NNZ_EDGES + 255) / 256, 256, 0, stream>>>(
      ui_rows, ui_cols, user_cur, item_cur, NNZ_EDGES);
  scan_kernel<<<2, 1024, 0, stream>>>(user_cur, user_off, item_cur, item_off);
  scatter_kernel<<<(NNZ_EDGES + 255) / 256, 256, 0, stream>>>(
      ui_rows, ui_cols, ui_vals, user_cur, item_cur, edges_u, edges_i, NNZ_EDGES);

  // Segmented SpMM + fused ReLU (writes every output element; no memset).
  spmm_csr_kernel<<<(N_USERS + 3) / 4, 256, 0, stream>>>(
      user_off, edges_u, xw_item, out_user, N_USERS);
  spmm_csr_kernel<<<(N_ITEMS + 3) / 4, 256, 0, stream>>>(
      item_off, edges_i, xw_user, out_item, N_ITEMS);
}